// Round 11
// baseline (317.035 us; speedup 1.0000x reference)
//
#include <hip/hip_runtime.h>
#include <stdint.h>

#define N_NODES 20000
#define N_EDGES 160000
#define N_GRAPHS 64
#define IN_DIM 128
#define HID 512
#define N_ACT 32

#define SCAN_NB ((N_NODES + 255) / 256)   // 79

typedef __attribute__((ext_vector_type(8))) short short8;
typedef __attribute__((ext_vector_type(4))) float f32x4;

__device__ __forceinline__ float bf2f(uint h16) {
    union { uint u; float f; } v; v.u = h16 << 16; return v.f;
}
__device__ __forceinline__ float bflo(uint u) {
    union { uint x; float f; } v; v.x = u << 16; return v.f;
}
__device__ __forceinline__ float bfhi(uint u) {
    union { uint x; float f; } v; v.x = u & 0xffff0000u; return v.f;
}
__device__ __forceinline__ ushort f2bf(float f) {
    union { float f; uint u; } v; v.f = f;
    uint u = v.u;
    uint r = (u + 0x7fffu + ((u >> 16) & 1u)) >> 16;
    return (ushort)r;
}

// ---------------- fused independent preprocessing ----------------
// block ranges: [0,625) hist | [625,10625) f2bf | [10625,10689) wt1 tiles
// [10689,10945) wt2 tiles | [10945,11201) wt3 tiles | [11201,11280) bounds

#define PB_HIST   625
#define PB_F2BF   (PB_HIST + 10000)
#define PB_WT1    (PB_F2BF + 64)
#define PB_WT2    (PB_WT1 + 256)
#define PB_WT3    (PB_WT2 + 256)
#define PB_BOUNDS (PB_WT3 + SCAN_NB)

__global__ __launch_bounds__(256) void k_prep(
    const int* __restrict__ edst, int* __restrict__ cnt,
    const float* __restrict__ tree_x, ushort* __restrict__ xbf,
    const float* __restrict__ W1, ushort* __restrict__ w1t,
    const float* __restrict__ W2, ushort* __restrict__ w2t,
    const float* __restrict__ W3, ushort* __restrict__ w3t,
    const int* __restrict__ batch, int* __restrict__ gstart)
{
    __shared__ float lds[32][33];
    int b = blockIdx.x;
    int t = threadIdx.x;
    int r = t >> 5, c = t & 31;     // 8 x 32
    if (b < PB_HIST) {
        int e = b * 256 + t;
        if (e < N_EDGES) atomicAdd(&cnt[edst[e]], 1);
    } else if (b < PB_F2BF) {
        int i = (b - PB_HIST) * 256 + t;
        if (i < N_NODES * IN_DIM) xbf[i] = f2bf(tree_x[i]);
    } else if (b < PB_WT1) {
        // W1 [128,512] f32 -> w1t [512,128] bf16, 32x32 tiles (4 x 16)
        int tt = b - PB_F2BF;
        int kt = tt & 3, nt = tt >> 2;
        for (int rr = r; rr < 32; rr += 8)
            lds[rr][c] = W1[(size_t)(kt * 32 + rr) * HID + nt * 32 + c];
        __syncthreads();
        for (int rr = r; rr < 32; rr += 8)
            w1t[(size_t)(nt * 32 + rr) * IN_DIM + kt * 32 + c] = f2bf(lds[c][rr]);
    } else if (b < PB_WT2) {
        int tt = b - PB_WT1;
        int kt = tt & 15, nt = tt >> 4;
        for (int rr = r; rr < 32; rr += 8)
            lds[rr][c] = W2[(size_t)(kt * 32 + rr) * HID + nt * 32 + c];
        __syncthreads();
        for (int rr = r; rr < 32; rr += 8)
            w2t[(size_t)(nt * 32 + rr) * HID + kt * 32 + c] = f2bf(lds[c][rr]);
    } else if (b < PB_WT3) {
        int tt = b - PB_WT2;
        int kt = tt & 15, nt = tt >> 4;
        for (int rr = r; rr < 32; rr += 8)
            lds[rr][c] = W3[(size_t)(kt * 32 + rr) * HID + nt * 32 + c];
        __syncthreads();
        for (int rr = r; rr < 32; rr += 8)
            w3t[(size_t)(nt * 32 + rr) * HID + kt * 32 + c] = f2bf(lds[c][rr]);
    } else {
        int i = (b - PB_WT3) * 256 + t;
        if (i < N_NODES) {
            if (i == 0) {
                gstart[batch[0]] = 0;
                gstart[N_GRAPHS] = N_NODES;
            } else if (batch[i] != batch[i - 1]) {
                gstart[batch[i]] = i;
            }
        }
    }
}

// ---------------- parallel scan: cnt -> rowstart/cursor/dinv ----------------

__global__ __launch_bounds__(256) void k_part(const int* __restrict__ cnt, int* __restrict__ bsum) {
    __shared__ int s[256];
    int idx = blockIdx.x * 256 + threadIdx.x;
    s[threadIdx.x] = (idx < N_NODES) ? cnt[idx] : 0;
    __syncthreads();
    for (int off = 128; off > 0; off >>= 1) {
        if (threadIdx.x < off) s[threadIdx.x] += s[threadIdx.x + off];
        __syncthreads();
    }
    if (threadIdx.x == 0) bsum[blockIdx.x] = s[0];
}

__global__ __launch_bounds__(128) void k_scanb(const int* __restrict__ bsum,
                                               int* __restrict__ boff, int* __restrict__ rowstart) {
    __shared__ int s[128];
    int t = threadIdx.x;
    int own = (t < SCAN_NB) ? bsum[t] : 0;
    s[t] = own;
    __syncthreads();
    for (int off = 1; off < 128; off <<= 1) {
        int v = 0;
        if (t >= off) v = s[t - off];
        __syncthreads();
        s[t] += v;
        __syncthreads();
    }
    if (t < SCAN_NB) boff[t] = s[t] - own;
    if (t == SCAN_NB - 1) rowstart[N_NODES] = s[t];
}

__global__ __launch_bounds__(256) void k_final(
    const int* __restrict__ cnt, const int* __restrict__ boff,
    int* __restrict__ rowstart, int* __restrict__ cursor, float* __restrict__ dinv)
{
    __shared__ int s[256];
    int t = threadIdx.x;
    int idx = blockIdx.x * 256 + t;
    int c = (idx < N_NODES) ? cnt[idx] : 0;
    s[t] = c;
    __syncthreads();
    for (int off = 1; off < 256; off <<= 1) {
        int v = 0;
        if (t >= off) v = s[t - off];
        __syncthreads();
        s[t] += v;
        __syncthreads();
    }
    if (idx < N_NODES) {
        int start = boff[blockIdx.x] + s[t] - c;   // exclusive
        rowstart[idx] = start;
        cursor[idx] = start;
        dinv[idx] = rsqrtf((float)c + 1.0f);
    }
}

__global__ void k_fill(const int* __restrict__ src, const int* __restrict__ dst,
                       int* __restrict__ cursor, int* __restrict__ csr_src) {
    int e = blockIdx.x * 256 + threadIdx.x;
    if (e < N_EDGES) {
        int p = atomicAdd(&cursor[dst[e]], 1);
        csr_src[p] = src[e];
    }
}

// ---------------- GEMM: Out[M,512] = epi(A[M,K]bf16 @ Bt[512,K]bf16^T) ----------------
// mode 0: *dinv[row]   (pre-aggregation scaling, layers 2/3)
// mode 1: +bias, relu  (post-aggregation, layer 1)

__global__ __launch_bounds__(256) void k_gemm(
    const ushort* __restrict__ A, const ushort* __restrict__ Bt,
    const float* __restrict__ dinv, const float* __restrict__ bias,
    ushort* __restrict__ Out, int M, int Kdim, int mode)
{
    const int N = HID;
    __shared__ __align__(16) ushort lA[128 * 64];
    __shared__ __align__(16) ushort lB[128 * 64];
    int bm = blockIdx.x, bn = blockIdx.y;
    int tid = threadIdx.x;
    int wave = tid >> 6, lane = tid & 63;
    int wm = (wave >> 1) * 64, wn = (wave & 1) * 64;

    f32x4 acc[4][4] = {};

    int srow = lane >> 3;          // 0..7 within an 8-row chunk
    int scol = (lane & 7) * 8;     // element offset of this lane's 16B within a 64-elem row

    for (int kt = 0; kt < Kdim; kt += 64) {
        for (int c = wave * 4; c < wave * 4 + 4; ++c) {
            int row = c * 8 + srow;
            int ga = bm * 128 + row; if (ga >= M) ga = M - 1;
            const ushort* gsA = A + (size_t)ga * Kdim + kt + scol;
            __builtin_amdgcn_global_load_lds(
                (const __attribute__((address_space(1))) void*)gsA,
                (__attribute__((address_space(3))) void*)(lA + c * 512), 16, 0, 0);
            int gb = bn * 128 + row; // N=512 exact, no clamp needed
            const ushort* gsB = Bt + (size_t)gb * Kdim + kt + scol;
            __builtin_amdgcn_global_load_lds(
                (const __attribute__((address_space(1))) void*)gsB,
                (__attribute__((address_space(3))) void*)(lB + c * 512), 16, 0, 0);
        }
        __syncthreads();
        for (int kk = 0; kk < 2; ++kk) {
            short8 af[4], bfr[4];
            int ko = kk * 32 + (lane >> 4) * 8;
            for (int m = 0; m < 4; ++m)
                af[m] = *(const short8*)&lA[(wm + m * 16 + (lane & 15)) * 64 + ko];
            for (int n = 0; n < 4; ++n)
                bfr[n] = *(const short8*)&lB[(wn + n * 16 + (lane & 15)) * 64 + ko];
            for (int m = 0; m < 4; ++m)
                for (int n = 0; n < 4; ++n)
                    acc[m][n] = __builtin_amdgcn_mfma_f32_16x16x32_bf16(af[m], bfr[n], acc[m][n], 0, 0, 0);
        }
        __syncthreads();
    }

    // epilogue: C row = (lane>>4)*4 + reg, col = lane&15
    int cb = bn * 128 + wn + (lane & 15);
    float bb[4];
    if (mode == 1) {
        for (int n = 0; n < 4; ++n) bb[n] = bias[cb + n * 16];
    }
    for (int m = 0; m < 4; ++m) {
        int rbase = bm * 128 + wm + m * 16 + (lane >> 4) * 4;
        for (int j = 0; j < 4; ++j) {
            int r = rbase + j;
            if (r < M) {
                if (mode == 0) {
                    float dv = dinv[r];
                    for (int n = 0; n < 4; ++n)
                        Out[(size_t)r * N + cb + n * 16] = f2bf(acc[m][n][j] * dv);
                } else {
                    for (int n = 0; n < 4; ++n)
                        Out[(size_t)r * N + cb + n * 16] = f2bf(fmaxf(acc[m][n][j] + bb[n], 0.0f));
                }
            }
        }
    }
}

// ---------------- layer-1 aggregation on 128-dim input (agg-first) ----------------
// Y[i] = bf16( dinv[i] * ( sum_e dinv[src_e]*X[src_e] + dinv[i]*X[i] ) )
// 4 nodes per block (wave per node), 4-edge unroll

__global__ __launch_bounds__(256) void k_agg1(
    const ushort* __restrict__ Xin, const int* __restrict__ rowstart,
    const int* __restrict__ csr_src, const float* __restrict__ dinv,
    ushort* __restrict__ Y)
{
    int i = blockIdx.x * 4 + (threadIdx.x >> 6);
    if (i >= N_NODES) return;
    int lane = threadIdx.x & 63;
    const uint* xin = (const uint*)Xin;        // 2 bf16 per uint, 64 uints per row
    float dv = dinv[i];
    uint xi = xin[(size_t)i * 64 + lane];
    float a0 = dv * bflo(xi), a1 = dv * bfhi(xi);
    int e = rowstart[i], s1 = rowstart[i + 1];
    for (; e + 4 <= s1; e += 4) {
        int sa = csr_src[e], sb = csr_src[e + 1], sc = csr_src[e + 2], sd = csr_src[e + 3];
        float da = dinv[sa], db = dinv[sb], dc = dinv[sc], dd = dinv[sd];
        uint wa = xin[(size_t)sa * 64 + lane];
        uint wb = xin[(size_t)sb * 64 + lane];
        uint wc = xin[(size_t)sc * 64 + lane];
        uint wd = xin[(size_t)sd * 64 + lane];
        a0 = fmaf(da, bflo(wa), a0); a1 = fmaf(da, bfhi(wa), a1);
        a0 = fmaf(db, bflo(wb), a0); a1 = fmaf(db, bfhi(wb), a1);
        a0 = fmaf(dc, bflo(wc), a0); a1 = fmaf(dc, bfhi(wc), a1);
        a0 = fmaf(dd, bflo(wd), a0); a1 = fmaf(dd, bfhi(wd), a1);
    }
    for (; e < s1; ++e) {
        int sa = csr_src[e];
        float da = dinv[sa];
        uint wa = xin[(size_t)sa * 64 + lane];
        a0 = fmaf(da, bflo(wa), a0); a1 = fmaf(da, bfhi(wa), a1);
    }
    uint o = (uint)f2bf(dv * a0) | ((uint)f2bf(dv * a1) << 16);
    ((uint*)Y)[(size_t)i * 64 + lane] = o;
}

// ---------------- 512-dim aggregation, column-split for per-XCD L2 residency ----------------
// grid (N/4, 8): wave = node, blockIdx.y = 64-channel group (2.5MB gbuf slice < 4MB L2).
// Half-wave per edge: lanes 0-31 even edges, 32-63 odd edges; combine via shfl_xor(32).
// X[i] = relu(dinv[i]*(sum_e g[src_e] + g[i]) + b)

__global__ __launch_bounds__(256) void k_agg_cs(
    const ushort* __restrict__ G, const int* __restrict__ rowstart,
    const int* __restrict__ csr_src, const float* __restrict__ dinv,
    const float* __restrict__ bias, ushort* __restrict__ X)
{
    int i = blockIdx.x * 4 + (threadIdx.x >> 6);
    int lane = threadIdx.x & 63;
    int half = lane >> 5;          // 0: even edges, 1: odd edges
    int cl = lane & 31;            // uint index within the 64-ch group
    int cg = blockIdx.y;           // column group 0..7
    const uint* gu = (const uint*)G;            // 256 uints per row
    size_t colbase = (size_t)cg * 32 + cl;

    // self term (counted once, by half 0)
    uint sv = gu[(size_t)i * 256 + colbase];
    float a0 = half ? 0.0f : bflo(sv);
    float a1 = half ? 0.0f : bfhi(sv);

    int e0 = rowstart[i], e1 = rowstart[i + 1];
    int e = e0 + half;
    for (; e + 4 <= e1; e += 4) {  // this half does e and e+2
        int sa = csr_src[e], sb = csr_src[e + 2];
        uint va = gu[(size_t)sa * 256 + colbase];
        uint vb = gu[(size_t)sb * 256 + colbase];
        a0 += bflo(va); a1 += bfhi(va);
        a0 += bflo(vb); a1 += bfhi(vb);
    }
    for (; e < e1; e += 2) {
        int sa = csr_src[e];
        uint va = gu[(size_t)sa * 256 + colbase];
        a0 += bflo(va); a1 += bfhi(va);
    }

    // combine even/odd halves
    a0 += __shfl_xor(a0, 32);
    a1 += __shfl_xor(a1, 32);

    if (half == 0) {
        float dv = dinv[i];
        float2 bb = ((const float2*)bias)[colbase];
        uint o = (uint)f2bf(fmaxf(fmaf(dv, a0, bb.x), 0.0f))
               | ((uint)f2bf(fmaxf(fmaf(dv, a1, bb.y), 0.0f)) << 16);
        ((uint*)X)[(size_t)i * 256 + colbase] = o;
    }
}

// ---------------- pooling: grid (N_GRAPHS, 8), lane owns one channel ----------------

__global__ __launch_bounds__(64) void k_pool(
    const ushort* __restrict__ X, const int* __restrict__ gstart, float* __restrict__ P)
{
    int g = blockIdx.x;
    int ch = blockIdx.y * 64 + threadIdx.x;
    float mx = -1e30f;
    int i0 = gstart[g], i1 = gstart[g + 1];
    int i = i0;
    for (; i + 4 <= i1; i += 4) {
        float a = bf2f(X[(size_t)(i + 0) * HID + ch]);
        float b = bf2f(X[(size_t)(i + 1) * HID + ch]);
        float c = bf2f(X[(size_t)(i + 2) * HID + ch]);
        float d = bf2f(X[(size_t)(i + 3) * HID + ch]);
        mx = fmaxf(mx, fmaxf(fmaxf(a, b), fmaxf(c, d)));
    }
    for (; i < i1; ++i) mx = fmaxf(mx, bf2f(X[(size_t)i * HID + ch]));
    P[(size_t)g * HID + ch] = mx;
}

// ---------------- FC layers: grid (graph, out-chunk of 64), 4 waves split K ----------------

__global__ __launch_bounds__(256) void k_fc(
    const float* __restrict__ in, const float* __restrict__ W,
    const float* __restrict__ b, float* __restrict__ out,
    int K, int NO, int relu)
{
    __shared__ float xs[HID];
    __shared__ float part[4][64];
    int g = blockIdx.x;
    int j0 = blockIdx.y * 64;
    int tid = threadIdx.x;
    int wave = tid >> 6, lane = tid & 63;

    for (int k = tid; k < K; k += 256) xs[k] = in[(size_t)g * K + k];
    __syncthreads();

    int j = j0 + lane;
    bool active = (j < NO);
    int kpw = K >> 2;          // K per wave (K=512 -> 128)
    int k0 = wave * kpw;
    float acc = 0.0f;
    if (active) {
        const float* wp = W + (size_t)k0 * NO + j;
        int k = 0;
        for (; k + 4 <= kpw; k += 4) {
            float w0 = wp[(size_t)(k + 0) * NO];
            float w1 = wp[(size_t)(k + 1) * NO];
            float w2 = wp[(size_t)(k + 2) * NO];
            float w3 = wp[(size_t)(k + 3) * NO];
            acc = fmaf(xs[k0 + k + 0], w0, acc);
            acc = fmaf(xs[k0 + k + 1], w1, acc);
            acc = fmaf(xs[k0 + k + 2], w2, acc);
            acc = fmaf(xs[k0 + k + 3], w3, acc);
        }
        for (; k < kpw; ++k)
            acc = fmaf(xs[k0 + k], wp[(size_t)k * NO], acc);
    }
    part[wave][lane] = acc;
    __syncthreads();
    if (wave == 0 && active) {
        float a = part[0][lane] + part[1][lane] + part[2][lane] + part[3][lane] + b[j];
        if (relu) a = fmaxf(a, 0.0f);
        out[(size_t)g * NO + j] = a;
    }
}

// ---------------- launch ----------------

extern "C" void kernel_launch(void* const* d_in, const int* in_sizes, int n_in,
                              void* d_out, int out_size, void* d_ws, size_t ws_size,
                              hipStream_t stream) {
    const float* tree_x = (const float*)d_in[0];
    const int*   ei     = (const int*)d_in[1];
    const int*   batch  = (const int*)d_in[2];
    const float* W1  = (const float*)d_in[3];  const float* b1  = (const float*)d_in[4];
    const float* W2  = (const float*)d_in[5];  const float* b2  = (const float*)d_in[6];
    const float* W3  = (const float*)d_in[7];  const float* b3  = (const float*)d_in[8];
    const float* Wf1 = (const float*)d_in[9];  const float* bf1 = (const float*)d_in[10];
    const float* Wf2 = (const float*)d_in[11]; const float* bf2 = (const float*)d_in[12];
    const float* Wf3 = (const float*)d_in[13]; const float* bf3 = (const float*)d_in[14];
    const float* Wo  = (const float*)d_in[15]; const float* bo  = (const float*)d_in[16];

    char* w = (char*)d_ws;
    size_t off = 0;
    auto alloc = [&](size_t bytes) -> void* {
        void* p = w + off;
        off += (bytes + 255) & ~(size_t)255;
        return p;
    };
    int*    cnt      = (int*)alloc((size_t)N_NODES * 4);
    int*    cursor   = (int*)alloc((size_t)N_NODES * 4);
    int*    rowstart = (int*)alloc((size_t)(N_NODES + 1) * 4);
    float*  dinv     = (float*)alloc((size_t)N_NODES * 4);
    int*    csr      = (int*)alloc((size_t)N_EDGES * 4);
    int*    gstart   = (int*)alloc((size_t)(N_GRAPHS + 1) * 4);
    int*    bsum     = (int*)alloc((size_t)SCAN_NB * 4);
    int*    boff     = (int*)alloc((size_t)SCAN_NB * 4);
    ushort* xbf      = (ushort*)alloc((size_t)N_NODES * IN_DIM * 2);
    ushort* ybuf     = (ushort*)alloc((size_t)N_NODES * IN_DIM * 2);
    ushort* w1t      = (ushort*)alloc((size_t)HID * IN_DIM * 2);
    ushort* w2t      = (ushort*)alloc((size_t)HID * HID * 2);
    ushort* w3t      = (ushort*)alloc((size_t)HID * HID * 2);
    ushort* gbuf     = (ushort*)alloc((size_t)N_NODES * HID * 2);
    ushort* xbuf     = (ushort*)alloc((size_t)N_NODES * HID * 2);
    float*  P0       = (float*)alloc((size_t)N_GRAPHS * HID * 4);
    float*  P1       = (float*)alloc((size_t)N_GRAPHS * HID * 4);

    const int* esrc = ei;
    const int* edst = ei + N_EDGES;

    hipMemsetAsync(cnt, 0, (size_t)N_NODES * 4, stream);
    k_prep<<<PB_BOUNDS, 256, 0, stream>>>(edst, cnt, tree_x, xbf,
                                          W1, w1t, W2, w2t, W3, w3t, batch, gstart);
    k_part<<<SCAN_NB, 256, 0, stream>>>(cnt, bsum);
    k_scanb<<<1, 128, 0, stream>>>(bsum, boff, rowstart);
    k_final<<<SCAN_NB, 256, 0, stream>>>(cnt, boff, rowstart, cursor, dinv);
    k_fill<<<(N_EDGES + 255) / 256, 256, 0, stream>>>(esrc, edst, cursor, csr);

    dim3 gemm_grid((N_NODES + 127) / 128, HID / 128);
    dim3 agg_grid(N_NODES / 4, 8);

    // layer 1: agg-first (128-dim gather), then GEMM with fused bias+relu
    k_agg1<<<N_NODES / 4, 256, 0, stream>>>(xbf, rowstart, csr, dinv, ybuf);
    k_gemm<<<gemm_grid, 256, 0, stream>>>(ybuf, w1t, dinv, b1, xbuf, N_NODES, IN_DIM, 1);
    // layer 2
    k_gemm<<<gemm_grid, 256, 0, stream>>>(xbuf, w2t, dinv, b2, gbuf, N_NODES, HID, 0);
    k_agg_cs<<<agg_grid, 256, 0, stream>>>(gbuf, rowstart, csr, dinv, b2, xbuf);
    // layer 3
    k_gemm<<<gemm_grid, 256, 0, stream>>>(xbuf, w3t, dinv, b3, gbuf, N_NODES, HID, 0);
    k_agg_cs<<<agg_grid, 256, 0, stream>>>(gbuf, rowstart, csr, dinv, b3, xbuf);

    // pool
    k_pool<<<dim3(N_GRAPHS, 8), 64, 0, stream>>>(xbuf, gstart, P0);

    // FC head
    k_fc<<<dim3(N_GRAPHS, HID / 64), 256, 0, stream>>>(P0, Wf1, bf1, P1, HID, HID, 1);
    k_fc<<<dim3(N_GRAPHS, HID / 64), 256, 0, stream>>>(P1, Wf2, bf2, P0, HID, HID, 1);
    k_fc<<<dim3(N_GRAPHS, HID / 64), 256, 0, stream>>>(P0, Wf3, bf3, P1, HID, HID, 1);
    k_fc<<<dim3(N_GRAPHS, 1), 256, 0, stream>>>(P1, Wo, bo, (float*)d_out, HID, N_ACT, 0);
}

// Round 12
// 235.502 us; speedup vs baseline: 1.3462x; 1.3462x over previous
//
#include <hip/hip_runtime.h>
#include <stdint.h>

#define N_NODES 20000
#define N_EDGES 160000
#define N_GRAPHS 64
#define IN_DIM 128
#define HID 512
#define N_ACT 32

#define SCAN_NB ((N_NODES + 255) / 256)   // 79

typedef __attribute__((ext_vector_type(8))) short short8;
typedef __attribute__((ext_vector_type(4))) float f32x4;

__device__ __forceinline__ float bf2f(uint h16) {
    union { uint u; float f; } v; v.u = h16 << 16; return v.f;
}
__device__ __forceinline__ float bflo(uint u) {
    union { uint x; float f; } v; v.x = u << 16; return v.f;
}
__device__ __forceinline__ float bfhi(uint u) {
    union { uint x; float f; } v; v.x = u & 0xffff0000u; return v.f;
}
__device__ __forceinline__ ushort f2bf(float f) {
    union { float f; uint u; } v; v.f = f;
    uint u = v.u;
    uint r = (u + 0x7fffu + ((u >> 16) & 1u)) >> 16;
    return (ushort)r;
}

__device__ __forceinline__ void add8(float* acc, uint4 v) {
    acc[0] += bflo(v.x); acc[1] += bfhi(v.x);
    acc[2] += bflo(v.y); acc[3] += bfhi(v.y);
    acc[4] += bflo(v.z); acc[5] += bfhi(v.z);
    acc[6] += bflo(v.w); acc[7] += bfhi(v.w);
}

// ---------------- fused independent preprocessing ----------------
// block ranges: [0,625) hist | [625,10625) f2bf | [10625,10689) wt1 tiles
// [10689,10945) wt2 tiles | [10945,11201) wt3 tiles | [11201,11280) bounds

#define PB_HIST   625
#define PB_F2BF   (PB_HIST + 10000)
#define PB_WT1    (PB_F2BF + 64)
#define PB_WT2    (PB_WT1 + 256)
#define PB_WT3    (PB_WT2 + 256)
#define PB_BOUNDS (PB_WT3 + SCAN_NB)

__global__ __launch_bounds__(256) void k_prep(
    const int* __restrict__ edst, int* __restrict__ cnt,
    const float* __restrict__ tree_x, ushort* __restrict__ xbf,
    const float* __restrict__ W1, ushort* __restrict__ w1t,
    const float* __restrict__ W2, ushort* __restrict__ w2t,
    const float* __restrict__ W3, ushort* __restrict__ w3t,
    const int* __restrict__ batch, int* __restrict__ gstart)
{
    __shared__ float lds[32][33];
    int b = blockIdx.x;
    int t = threadIdx.x;
    int r = t >> 5, c = t & 31;     // 8 x 32
    if (b < PB_HIST) {
        int e = b * 256 + t;
        if (e < N_EDGES) atomicAdd(&cnt[edst[e]], 1);
    } else if (b < PB_F2BF) {
        int i = (b - PB_HIST) * 256 + t;
        if (i < N_NODES * IN_DIM) xbf[i] = f2bf(tree_x[i]);
    } else if (b < PB_WT1) {
        // W1 [128,512] f32 -> w1t [512,128] bf16, 32x32 tiles (4 x 16)
        int tt = b - PB_F2BF;
        int kt = tt & 3, nt = tt >> 2;
        for (int rr = r; rr < 32; rr += 8)
            lds[rr][c] = W1[(size_t)(kt * 32 + rr) * HID + nt * 32 + c];
        __syncthreads();
        for (int rr = r; rr < 32; rr += 8)
            w1t[(size_t)(nt * 32 + rr) * IN_DIM + kt * 32 + c] = f2bf(lds[c][rr]);
    } else if (b < PB_WT2) {
        int tt = b - PB_WT1;
        int kt = tt & 15, nt = tt >> 4;
        for (int rr = r; rr < 32; rr += 8)
            lds[rr][c] = W2[(size_t)(kt * 32 + rr) * HID + nt * 32 + c];
        __syncthreads();
        for (int rr = r; rr < 32; rr += 8)
            w2t[(size_t)(nt * 32 + rr) * HID + kt * 32 + c] = f2bf(lds[c][rr]);
    } else if (b < PB_WT3) {
        int tt = b - PB_WT2;
        int kt = tt & 15, nt = tt >> 4;
        for (int rr = r; rr < 32; rr += 8)
            lds[rr][c] = W3[(size_t)(kt * 32 + rr) * HID + nt * 32 + c];
        __syncthreads();
        for (int rr = r; rr < 32; rr += 8)
            w3t[(size_t)(nt * 32 + rr) * HID + kt * 32 + c] = f2bf(lds[c][rr]);
    } else {
        int i = (b - PB_WT3) * 256 + t;
        if (i < N_NODES) {
            if (i == 0) {
                gstart[batch[0]] = 0;
                gstart[N_GRAPHS] = N_NODES;
            } else if (batch[i] != batch[i - 1]) {
                gstart[batch[i]] = i;
            }
        }
    }
}

// ---------------- parallel scan: cnt -> rowstart/cursor/dinv ----------------

__global__ __launch_bounds__(256) void k_part(const int* __restrict__ cnt, int* __restrict__ bsum) {
    __shared__ int s[256];
    int idx = blockIdx.x * 256 + threadIdx.x;
    s[threadIdx.x] = (idx < N_NODES) ? cnt[idx] : 0;
    __syncthreads();
    for (int off = 128; off > 0; off >>= 1) {
        if (threadIdx.x < off) s[threadIdx.x] += s[threadIdx.x + off];
        __syncthreads();
    }
    if (threadIdx.x == 0) bsum[blockIdx.x] = s[0];
}

__global__ __launch_bounds__(128) void k_scanb(const int* __restrict__ bsum,
                                               int* __restrict__ boff, int* __restrict__ rowstart) {
    __shared__ int s[128];
    int t = threadIdx.x;
    int own = (t < SCAN_NB) ? bsum[t] : 0;
    s[t] = own;
    __syncthreads();
    for (int off = 1; off < 128; off <<= 1) {
        int v = 0;
        if (t >= off) v = s[t - off];
        __syncthreads();
        s[t] += v;
        __syncthreads();
    }
    if (t < SCAN_NB) boff[t] = s[t] - own;
    if (t == SCAN_NB - 1) rowstart[N_NODES] = s[t];
}

__global__ __launch_bounds__(256) void k_final(
    const int* __restrict__ cnt, const int* __restrict__ boff,
    int* __restrict__ rowstart, int* __restrict__ cursor, float* __restrict__ dinv)
{
    __shared__ int s[256];
    int t = threadIdx.x;
    int idx = blockIdx.x * 256 + t;
    int c = (idx < N_NODES) ? cnt[idx] : 0;
    s[t] = c;
    __syncthreads();
    for (int off = 1; off < 256; off <<= 1) {
        int v = 0;
        if (t >= off) v = s[t - off];
        __syncthreads();
        s[t] += v;
        __syncthreads();
    }
    if (idx < N_NODES) {
        int start = boff[blockIdx.x] + s[t] - c;   // exclusive
        rowstart[idx] = start;
        cursor[idx] = start;
        dinv[idx] = rsqrtf((float)c + 1.0f);
    }
}

__global__ void k_fill(const int* __restrict__ src, const int* __restrict__ dst,
                       int* __restrict__ cursor, int* __restrict__ csr_src) {
    int e = blockIdx.x * 256 + threadIdx.x;
    if (e < N_EDGES) {
        int p = atomicAdd(&cursor[dst[e]], 1);
        csr_src[p] = src[e];
    }
}

// ---------------- GEMM: Out[M,512] = epi(A[M,K]bf16 @ Bt[512,K]bf16^T) ----------------
// mode 0: *dinv[row]   (pre-aggregation scaling, layers 2/3)
// mode 1: +bias, relu  (post-aggregation, layer 1)

__global__ __launch_bounds__(256) void k_gemm(
    const ushort* __restrict__ A, const ushort* __restrict__ Bt,
    const float* __restrict__ dinv, const float* __restrict__ bias,
    ushort* __restrict__ Out, int M, int Kdim, int mode)
{
    const int N = HID;
    __shared__ __align__(16) ushort lA[128 * 64];
    __shared__ __align__(16) ushort lB[128 * 64];
    int bm = blockIdx.x, bn = blockIdx.y;
    int tid = threadIdx.x;
    int wave = tid >> 6, lane = tid & 63;
    int wm = (wave >> 1) * 64, wn = (wave & 1) * 64;

    f32x4 acc[4][4] = {};

    int srow = lane >> 3;          // 0..7 within an 8-row chunk
    int scol = (lane & 7) * 8;     // element offset of this lane's 16B within a 64-elem row

    for (int kt = 0; kt < Kdim; kt += 64) {
        for (int c = wave * 4; c < wave * 4 + 4; ++c) {
            int row = c * 8 + srow;
            int ga = bm * 128 + row; if (ga >= M) ga = M - 1;
            const ushort* gsA = A + (size_t)ga * Kdim + kt + scol;
            __builtin_amdgcn_global_load_lds(
                (const __attribute__((address_space(1))) void*)gsA,
                (__attribute__((address_space(3))) void*)(lA + c * 512), 16, 0, 0);
            int gb = bn * 128 + row; // N=512 exact, no clamp needed
            const ushort* gsB = Bt + (size_t)gb * Kdim + kt + scol;
            __builtin_amdgcn_global_load_lds(
                (const __attribute__((address_space(1))) void*)gsB,
                (__attribute__((address_space(3))) void*)(lB + c * 512), 16, 0, 0);
        }
        __syncthreads();
        for (int kk = 0; kk < 2; ++kk) {
            short8 af[4], bfr[4];
            int ko = kk * 32 + (lane >> 4) * 8;
            for (int m = 0; m < 4; ++m)
                af[m] = *(const short8*)&lA[(wm + m * 16 + (lane & 15)) * 64 + ko];
            for (int n = 0; n < 4; ++n)
                bfr[n] = *(const short8*)&lB[(wn + n * 16 + (lane & 15)) * 64 + ko];
            for (int m = 0; m < 4; ++m)
                for (int n = 0; n < 4; ++n)
                    acc[m][n] = __builtin_amdgcn_mfma_f32_16x16x32_bf16(af[m], bfr[n], acc[m][n], 0, 0, 0);
        }
        __syncthreads();
    }

    // epilogue: C row = (lane>>4)*4 + reg, col = lane&15
    int cb = bn * 128 + wn + (lane & 15);
    float bb[4];
    if (mode == 1) {
        for (int n = 0; n < 4; ++n) bb[n] = bias[cb + n * 16];
    }
    for (int m = 0; m < 4; ++m) {
        int rbase = bm * 128 + wm + m * 16 + (lane >> 4) * 4;
        for (int j = 0; j < 4; ++j) {
            int r = rbase + j;
            if (r < M) {
                if (mode == 0) {
                    float dv = dinv[r];
                    for (int n = 0; n < 4; ++n)
                        Out[(size_t)r * N + cb + n * 16] = f2bf(acc[m][n][j] * dv);
                } else {
                    for (int n = 0; n < 4; ++n)
                        Out[(size_t)r * N + cb + n * 16] = f2bf(fmaxf(acc[m][n][j] + bb[n], 0.0f));
                }
            }
        }
    }
}

// ---------------- layer-1 aggregation on 128-dim input (agg-first) ----------------
// Y[i] = bf16( dinv[i] * ( sum_e dinv[src_e]*X[src_e] + dinv[i]*X[i] ) )
// 4 nodes per block (wave per node), 4-edge unroll

__global__ __launch_bounds__(256) void k_agg1(
    const ushort* __restrict__ Xin, const int* __restrict__ rowstart,
    const int* __restrict__ csr_src, const float* __restrict__ dinv,
    ushort* __restrict__ Y)
{
    int i = blockIdx.x * 4 + (threadIdx.x >> 6);
    if (i >= N_NODES) return;
    int lane = threadIdx.x & 63;
    const uint* xin = (const uint*)Xin;        // 2 bf16 per uint, 64 uints per row
    float dv = dinv[i];
    uint xi = xin[(size_t)i * 64 + lane];
    float a0 = dv * bflo(xi), a1 = dv * bfhi(xi);
    int e = rowstart[i], s1 = rowstart[i + 1];
    for (; e + 4 <= s1; e += 4) {
        int sa = csr_src[e], sb = csr_src[e + 1], sc = csr_src[e + 2], sd = csr_src[e + 3];
        float da = dinv[sa], db = dinv[sb], dc = dinv[sc], dd = dinv[sd];
        uint wa = xin[(size_t)sa * 64 + lane];
        uint wb = xin[(size_t)sb * 64 + lane];
        uint wc = xin[(size_t)sc * 64 + lane];
        uint wd = xin[(size_t)sd * 64 + lane];
        a0 = fmaf(da, bflo(wa), a0); a1 = fmaf(da, bfhi(wa), a1);
        a0 = fmaf(db, bflo(wb), a0); a1 = fmaf(db, bfhi(wb), a1);
        a0 = fmaf(dc, bflo(wc), a0); a1 = fmaf(dc, bfhi(wc), a1);
        a0 = fmaf(dd, bflo(wd), a0); a1 = fmaf(dd, bfhi(wd), a1);
    }
    for (; e < s1; ++e) {
        int sa = csr_src[e];
        float da = dinv[sa];
        uint wa = xin[(size_t)sa * 64 + lane];
        a0 = fmaf(da, bflo(wa), a0); a1 = fmaf(da, bfhi(wa), a1);
    }
    uint o = (uint)f2bf(dv * a0) | ((uint)f2bf(dv * a1) << 16);
    ((uint*)Y)[(size_t)i * 64 + lane] = o;
}

// ---------------- 512-dim aggregation: X[i] = relu(dinv[i]*(sum_e g[src_e] + g[i]) + b) ----------------
// 4 nodes per block (wave per node), 8-edge unroll, uint4 full-row gathers

__global__ __launch_bounds__(256) void k_agg(
    const ushort* __restrict__ G, const int* __restrict__ rowstart,
    const int* __restrict__ csr_src, const float* __restrict__ dinv,
    const float* __restrict__ bias, ushort* __restrict__ X)
{
    int i = blockIdx.x * 4 + (threadIdx.x >> 6);
    if (i >= N_NODES) return;
    int lane = threadIdx.x & 63;
    const uint4* g4 = (const uint4*)G;         // 8 bf16 per uint4, 64 per row

    uint4 a = g4[(size_t)i * 64 + lane];
    float acc[8] = { bflo(a.x), bfhi(a.x), bflo(a.y), bfhi(a.y),
                     bflo(a.z), bfhi(a.z), bflo(a.w), bfhi(a.w) };

    int e = rowstart[i], s1 = rowstart[i + 1];
    for (; e + 8 <= s1; e += 8) {
        int s0 = csr_src[e],     s1i = csr_src[e + 1], s2 = csr_src[e + 2], s3 = csr_src[e + 3];
        int s4 = csr_src[e + 4], s5 = csr_src[e + 5],  s6 = csr_src[e + 6], s7 = csr_src[e + 7];
        uint4 w0 = g4[(size_t)s0 * 64 + lane];
        uint4 w1 = g4[(size_t)s1i * 64 + lane];
        uint4 w2 = g4[(size_t)s2 * 64 + lane];
        uint4 w3 = g4[(size_t)s3 * 64 + lane];
        uint4 w4 = g4[(size_t)s4 * 64 + lane];
        uint4 w5 = g4[(size_t)s5 * 64 + lane];
        uint4 w6 = g4[(size_t)s6 * 64 + lane];
        uint4 w7 = g4[(size_t)s7 * 64 + lane];
        add8(acc, w0); add8(acc, w1); add8(acc, w2); add8(acc, w3);
        add8(acc, w4); add8(acc, w5); add8(acc, w6); add8(acc, w7);
    }
    for (; e + 4 <= s1; e += 4) {
        int s0 = csr_src[e], s1i = csr_src[e + 1], s2 = csr_src[e + 2], s3 = csr_src[e + 3];
        uint4 w0 = g4[(size_t)s0 * 64 + lane];
        uint4 w1 = g4[(size_t)s1i * 64 + lane];
        uint4 w2 = g4[(size_t)s2 * 64 + lane];
        uint4 w3 = g4[(size_t)s3 * 64 + lane];
        add8(acc, w0); add8(acc, w1); add8(acc, w2); add8(acc, w3);
    }
    for (; e < s1; ++e) {
        int s0 = csr_src[e];
        uint4 w0 = g4[(size_t)s0 * 64 + lane];
        add8(acc, w0);
    }

    float dv = dinv[i];
    float4 b0 = *(const float4*)(bias + lane * 8);
    float4 b1 = *(const float4*)(bias + lane * 8 + 4);
    float bb[8] = { b0.x, b0.y, b0.z, b0.w, b1.x, b1.y, b1.z, b1.w };

    uint4 o;
    uint p[8];
    for (int j = 0; j < 8; ++j)
        p[j] = f2bf(fmaxf(fmaf(dv, acc[j], bb[j]), 0.0f));
    o.x = p[0] | (p[1] << 16);
    o.y = p[2] | (p[3] << 16);
    o.z = p[4] | (p[5] << 16);
    o.w = p[6] | (p[7] << 16);
    *(uint4*)(X + (size_t)i * HID + lane * 8) = o;
}

// ---------------- pooling: grid (N_GRAPHS, 8), 256 threads; 8 half-waves stride nodes ----------------
// X is post-relu (>=0), so 0-init max is exact.

__global__ __launch_bounds__(256) void k_pool(
    const ushort* __restrict__ X, const int* __restrict__ gstart, float* __restrict__ P)
{
    __shared__ float red[8][64];
    int g = blockIdx.x;
    int cg = blockIdx.y;           // 64-channel group
    int t = threadIdx.x;
    int hw = t >> 5;               // half-wave 0..7
    int cl = t & 31;               // uint lane: covers 2 channels
    const uint* xu = (const uint*)X;            // 256 uints per row
    size_t colbase = (size_t)cg * 32 + cl;
    int i0 = gstart[g], i1 = gstart[g + 1];
    float m0 = 0.0f, m1 = 0.0f;
    for (int i = i0 + hw; i < i1; i += 8) {
        uint v = xu[(size_t)i * 256 + colbase];
        m0 = fmaxf(m0, bflo(v));
        m1 = fmaxf(m1, bfhi(v));
    }
    red[hw][cl * 2] = m0;
    red[hw][cl * 2 + 1] = m1;
    __syncthreads();
    if (hw == 0) {
        float a = red[0][cl * 2], b = red[0][cl * 2 + 1];
        for (int q = 1; q < 8; ++q) {
            a = fmaxf(a, red[q][cl * 2]);
            b = fmaxf(b, red[q][cl * 2 + 1]);
        }
        P[(size_t)g * HID + cg * 64 + cl * 2] = a;
        P[(size_t)g * HID + cg * 64 + cl * 2 + 1] = b;
    }
}

// ---------------- FC layers: grid (graph, out-chunk of 64), 4 waves split K ----------------

__global__ __launch_bounds__(256) void k_fc(
    const float* __restrict__ in, const float* __restrict__ W,
    const float* __restrict__ b, float* __restrict__ out,
    int K, int NO, int relu)
{
    __shared__ float xs[HID];
    __shared__ float part[4][64];
    int g = blockIdx.x;
    int j0 = blockIdx.y * 64;
    int tid = threadIdx.x;
    int wave = tid >> 6, lane = tid & 63;

    for (int k = tid; k < K; k += 256) xs[k] = in[(size_t)g * K + k];
    __syncthreads();

    int j = j0 + lane;
    bool active = (j < NO);
    int kpw = K >> 2;          // K per wave (K=512 -> 128)
    int k0 = wave * kpw;
    float acc = 0.0f;
    if (active) {
        const float* wp = W + (size_t)k0 * NO + j;
        int k = 0;
        for (; k + 4 <= kpw; k += 4) {
            float w0 = wp[(size_t)(k + 0) * NO];
            float w1 = wp[(size_t)(k + 1) * NO];
            float w2 = wp[(size_t)(k + 2) * NO];
            float w3 = wp[(size_t)(k + 3) * NO];
            acc = fmaf(xs[k0 + k + 0], w0, acc);
            acc = fmaf(xs[k0 + k + 1], w1, acc);
            acc = fmaf(xs[k0 + k + 2], w2, acc);
            acc = fmaf(xs[k0 + k + 3], w3, acc);
        }
        for (; k < kpw; ++k)
            acc = fmaf(xs[k0 + k], wp[(size_t)k * NO], acc);
    }
    part[wave][lane] = acc;
    __syncthreads();
    if (wave == 0 && active) {
        float a = part[0][lane] + part[1][lane] + part[2][lane] + part[3][lane] + b[j];
        if (relu) a = fmaxf(a, 0.0f);
        out[(size_t)g * NO + j] = a;
    }
}

// ---------------- launch ----------------

extern "C" void kernel_launch(void* const* d_in, const int* in_sizes, int n_in,
                              void* d_out, int out_size, void* d_ws, size_t ws_size,
                              hipStream_t stream) {
    const float* tree_x = (const float*)d_in[0];
    const int*   ei     = (const int*)d_in[1];
    const int*   batch  = (const int*)d_in[2];
    const float* W1  = (const float*)d_in[3];  const float* b1  = (const float*)d_in[4];
    const float* W2  = (const float*)d_in[5];  const float* b2  = (const float*)d_in[6];
    const float* W3  = (const float*)d_in[7];  const float* b3  = (const float*)d_in[8];
    const float* Wf1 = (const float*)d_in[9];  const float* bf1 = (const float*)d_in[10];
    const float* Wf2 = (const float*)d_in[11]; const float* bf2 = (const float*)d_in[12];
    const float* Wf3 = (const float*)d_in[13]; const float* bf3 = (const float*)d_in[14];
    const float* Wo  = (const float*)d_in[15]; const float* bo  = (const float*)d_in[16];

    char* w = (char*)d_ws;
    size_t off = 0;
    auto alloc = [&](size_t bytes) -> void* {
        void* p = w + off;
        off += (bytes + 255) & ~(size_t)255;
        return p;
    };
    int*    cnt      = (int*)alloc((size_t)N_NODES * 4);
    int*    cursor   = (int*)alloc((size_t)N_NODES * 4);
    int*    rowstart = (int*)alloc((size_t)(N_NODES + 1) * 4);
    float*  dinv     = (float*)alloc((size_t)N_NODES * 4);
    int*    csr      = (int*)alloc((size_t)N_EDGES * 4);
    int*    gstart   = (int*)alloc((size_t)(N_GRAPHS + 1) * 4);
    int*    bsum     = (int*)alloc((size_t)SCAN_NB * 4);
    int*    boff     = (int*)alloc((size_t)SCAN_NB * 4);
    ushort* xbf      = (ushort*)alloc((size_t)N_NODES * IN_DIM * 2);
    ushort* ybuf     = (ushort*)alloc((size_t)N_NODES * IN_DIM * 2);
    ushort* w1t      = (ushort*)alloc((size_t)HID * IN_DIM * 2);
    ushort* w2t      = (ushort*)alloc((size_t)HID * HID * 2);
    ushort* w3t      = (ushort*)alloc((size_t)HID * HID * 2);
    ushort* gbuf     = (ushort*)alloc((size_t)N_NODES * HID * 2);
    ushort* xbuf     = (ushort*)alloc((size_t)N_NODES * HID * 2);
    float*  P0       = (float*)alloc((size_t)N_GRAPHS * HID * 4);
    float*  P1       = (float*)alloc((size_t)N_GRAPHS * HID * 4);

    const int* esrc = ei;
    const int* edst = ei + N_EDGES;

    hipMemsetAsync(cnt, 0, (size_t)N_NODES * 4, stream);
    k_prep<<<PB_BOUNDS, 256, 0, stream>>>(edst, cnt, tree_x, xbf,
                                          W1, w1t, W2, w2t, W3, w3t, batch, gstart);
    k_part<<<SCAN_NB, 256, 0, stream>>>(cnt, bsum);
    k_scanb<<<1, 128, 0, stream>>>(bsum, boff, rowstart);
    k_final<<<SCAN_NB, 256, 0, stream>>>(cnt, boff, rowstart, cursor, dinv);
    k_fill<<<(N_EDGES + 255) / 256, 256, 0, stream>>>(esrc, edst, cursor, csr);

    dim3 gemm_grid((N_NODES + 127) / 128, HID / 128);

    // layer 1: agg-first (128-dim gather), then GEMM with fused bias+relu
    k_agg1<<<N_NODES / 4, 256, 0, stream>>>(xbf, rowstart, csr, dinv, ybuf);
    k_gemm<<<gemm_grid, 256, 0, stream>>>(ybuf, w1t, dinv, b1, xbuf, N_NODES, IN_DIM, 1);
    // layer 2
    k_gemm<<<gemm_grid, 256, 0, stream>>>(xbuf, w2t, dinv, b2, gbuf, N_NODES, HID, 0);
    k_agg<<<N_NODES / 4, 256, 0, stream>>>(gbuf, rowstart, csr, dinv, b2, xbuf);
    // layer 3
    k_gemm<<<gemm_grid, 256, 0, stream>>>(xbuf, w3t, dinv, b3, gbuf, N_NODES, HID, 0);
    k_agg<<<N_NODES / 4, 256, 0, stream>>>(gbuf, rowstart, csr, dinv, b3, xbuf);

    // pool
    k_pool<<<dim3(N_GRAPHS, 8), 256, 0, stream>>>(xbuf, gstart, P0);

    // FC head
    k_fc<<<dim3(N_GRAPHS, HID / 64), 256, 0, stream>>>(P0, Wf1, bf1, P1, HID, HID, 1);
    k_fc<<<dim3(N_GRAPHS, HID / 64), 256, 0, stream>>>(P1, Wf2, bf2, P0, HID, HID, 1);
    k_fc<<<dim3(N_GRAPHS, HID / 64), 256, 0, stream>>>(P0, Wf3, bf3, P1, HID, HID, 1);
    k_fc<<<dim3(N_GRAPHS, 1), 256, 0, stream>>>(P1, Wo, bo, (float*)d_out, HID, N_ACT, 0);
}

// Round 13
// 220.178 us; speedup vs baseline: 1.4399x; 1.0696x over previous
//
#include <hip/hip_runtime.h>
#include <stdint.h>

#define N_NODES 20000
#define N_EDGES 160000
#define N_GRAPHS 64
#define IN_DIM 128
#define HID 512
#define N_ACT 32
#define SLOT_SHIFT 7                 // 128 slots per node
#define SLOTS (1 << SLOT_SHIFT)

typedef __attribute__((ext_vector_type(8))) short short8;
typedef __attribute__((ext_vector_type(4))) float f32x4;

__device__ __forceinline__ float bf2f(uint h16) {
    union { uint u; float f; } v; v.u = h16 << 16; return v.f;
}
__device__ __forceinline__ float bflo(uint u) {
    union { uint x; float f; } v; v.x = u << 16; return v.f;
}
__device__ __forceinline__ float bfhi(uint u) {
    union { uint x; float f; } v; v.x = u & 0xffff0000u; return v.f;
}
__device__ __forceinline__ ushort f2bf(float f) {
    union { float f; uint u; } v; v.f = f;
    uint u = v.u;
    uint r = (u + 0x7fffu + ((u >> 16) & 1u)) >> 16;
    return (ushort)r;
}
__device__ __forceinline__ float deg_inv(int c) {
    return rsqrtf((float)c + 1.0f);
}

__device__ __forceinline__ void add8(float* acc, uint4 v) {
    acc[0] += bflo(v.x); acc[1] += bfhi(v.x);
    acc[2] += bflo(v.y); acc[3] += bfhi(v.y);
    acc[4] += bflo(v.z); acc[5] += bfhi(v.z);
    acc[6] += bflo(v.w); acc[7] += bfhi(v.w);
}

// ---------------- fused preprocessing ----------------
// block ranges: [0,625) hist+bucket-fill | [625,10625) f2bf | [10625,10689) wt1 tiles
// [10689,10945) wt2 tiles | [10945,11201) wt3 tiles | [11201,11280) bounds

#define PB_HIST   625
#define PB_F2BF   (PB_HIST + 10000)
#define PB_WT1    (PB_F2BF + 64)
#define PB_WT2    (PB_WT1 + 256)
#define PB_WT3    (PB_WT2 + 256)
#define PB_BOUNDS (PB_WT3 + ((N_NODES + 255) / 256))

__global__ __launch_bounds__(256) void k_prep(
    const int* __restrict__ esrc, const int* __restrict__ edst,
    int* __restrict__ cnt, int* __restrict__ csr2,
    const float* __restrict__ tree_x, ushort* __restrict__ xbf,
    const float* __restrict__ W1, ushort* __restrict__ w1t,
    const float* __restrict__ W2, ushort* __restrict__ w2t,
    const float* __restrict__ W3, ushort* __restrict__ w3t,
    const int* __restrict__ batch, int* __restrict__ gstart)
{
    __shared__ float lds[32][33];
    int b = blockIdx.x;
    int t = threadIdx.x;
    int r = t >> 5, c = t & 31;     // 8 x 32
    if (b < PB_HIST) {
        int e = b * 256 + t;
        if (e < N_EDGES) {
            int d = edst[e];
            int slot = atomicAdd(&cnt[d], 1);
            csr2[((size_t)d << SLOT_SHIFT) + slot] = esrc[e];
        }
    } else if (b < PB_F2BF) {
        int i = (b - PB_HIST) * 256 + t;
        if (i < N_NODES * IN_DIM) xbf[i] = f2bf(tree_x[i]);
    } else if (b < PB_WT1) {
        // W1 [128,512] f32 -> w1t [512,128] bf16, 32x32 tiles (4 x 16)
        int tt = b - PB_F2BF;
        int kt = tt & 3, nt = tt >> 2;
        for (int rr = r; rr < 32; rr += 8)
            lds[rr][c] = W1[(size_t)(kt * 32 + rr) * HID + nt * 32 + c];
        __syncthreads();
        for (int rr = r; rr < 32; rr += 8)
            w1t[(size_t)(nt * 32 + rr) * IN_DIM + kt * 32 + c] = f2bf(lds[c][rr]);
    } else if (b < PB_WT2) {
        int tt = b - PB_WT1;
        int kt = tt & 15, nt = tt >> 4;
        for (int rr = r; rr < 32; rr += 8)
            lds[rr][c] = W2[(size_t)(kt * 32 + rr) * HID + nt * 32 + c];
        __syncthreads();
        for (int rr = r; rr < 32; rr += 8)
            w2t[(size_t)(nt * 32 + rr) * HID + kt * 32 + c] = f2bf(lds[c][rr]);
    } else if (b < PB_WT3) {
        int tt = b - PB_WT2;
        int kt = tt & 15, nt = tt >> 4;
        for (int rr = r; rr < 32; rr += 8)
            lds[rr][c] = W3[(size_t)(kt * 32 + rr) * HID + nt * 32 + c];
        __syncthreads();
        for (int rr = r; rr < 32; rr += 8)
            w3t[(size_t)(nt * 32 + rr) * HID + kt * 32 + c] = f2bf(lds[c][rr]);
    } else {
        int i = (b - PB_WT3) * 256 + t;
        if (i < N_NODES) {
            if (i == 0) {
                gstart[batch[0]] = 0;
                gstart[N_GRAPHS] = N_NODES;
            } else if (batch[i] != batch[i - 1]) {
                gstart[batch[i]] = i;
            }
        }
    }
}

// ---------------- GEMM: Out[M,512] = epi(A[M,K]bf16 @ Bt[512,K]bf16^T) ----------------
// mode 0: *dinv[row]   (pre-aggregation scaling, layers 2/3)
// mode 1: +bias, relu  (post-aggregation, layer 1)

__global__ __launch_bounds__(256) void k_gemm(
    const ushort* __restrict__ A, const ushort* __restrict__ Bt,
    const int* __restrict__ cnt, const float* __restrict__ bias,
    ushort* __restrict__ Out, int M, int Kdim, int mode)
{
    const int N = HID;
    __shared__ __align__(16) ushort lA[128 * 64];
    __shared__ __align__(16) ushort lB[128 * 64];
    int bm = blockIdx.x, bn = blockIdx.y;
    int tid = threadIdx.x;
    int wave = tid >> 6, lane = tid & 63;
    int wm = (wave >> 1) * 64, wn = (wave & 1) * 64;

    f32x4 acc[4][4] = {};

    int srow = lane >> 3;          // 0..7 within an 8-row chunk
    int scol = (lane & 7) * 8;     // element offset of this lane's 16B within a 64-elem row

    for (int kt = 0; kt < Kdim; kt += 64) {
        for (int c = wave * 4; c < wave * 4 + 4; ++c) {
            int row = c * 8 + srow;
            int ga = bm * 128 + row; if (ga >= M) ga = M - 1;
            const ushort* gsA = A + (size_t)ga * Kdim + kt + scol;
            __builtin_amdgcn_global_load_lds(
                (const __attribute__((address_space(1))) void*)gsA,
                (__attribute__((address_space(3))) void*)(lA + c * 512), 16, 0, 0);
            int gb = bn * 128 + row; // N=512 exact, no clamp needed
            const ushort* gsB = Bt + (size_t)gb * Kdim + kt + scol;
            __builtin_amdgcn_global_load_lds(
                (const __attribute__((address_space(1))) void*)gsB,
                (__attribute__((address_space(3))) void*)(lB + c * 512), 16, 0, 0);
        }
        __syncthreads();
        for (int kk = 0; kk < 2; ++kk) {
            short8 af[4], bfr[4];
            int ko = kk * 32 + (lane >> 4) * 8;
            for (int m = 0; m < 4; ++m)
                af[m] = *(const short8*)&lA[(wm + m * 16 + (lane & 15)) * 64 + ko];
            for (int n = 0; n < 4; ++n)
                bfr[n] = *(const short8*)&lB[(wn + n * 16 + (lane & 15)) * 64 + ko];
            for (int m = 0; m < 4; ++m)
                for (int n = 0; n < 4; ++n)
                    acc[m][n] = __builtin_amdgcn_mfma_f32_16x16x32_bf16(af[m], bfr[n], acc[m][n], 0, 0, 0);
        }
        __syncthreads();
    }

    // epilogue: C row = (lane>>4)*4 + reg, col = lane&15
    int cb = bn * 128 + wn + (lane & 15);
    float bb[4];
    if (mode == 1) {
        for (int n = 0; n < 4; ++n) bb[n] = bias[cb + n * 16];
    }
    for (int m = 0; m < 4; ++m) {
        int rbase = bm * 128 + wm + m * 16 + (lane >> 4) * 4;
        for (int j = 0; j < 4; ++j) {
            int r = rbase + j;
            if (r < M) {
                if (mode == 0) {
                    float dv = deg_inv(cnt[r]);
                    for (int n = 0; n < 4; ++n)
                        Out[(size_t)r * N + cb + n * 16] = f2bf(acc[m][n][j] * dv);
                } else {
                    for (int n = 0; n < 4; ++n)
                        Out[(size_t)r * N + cb + n * 16] = f2bf(fmaxf(acc[m][n][j] + bb[n], 0.0f));
                }
            }
        }
    }
}

// ---------------- layer-1 aggregation on 128-dim input (agg-first) ----------------
// Y[i] = bf16( dinv[i] * ( sum_e dinv[src_e]*X[src_e] + dinv[i]*X[i] ) )
// 4 nodes per block (wave per node), 4-edge unroll; bucket adjacency

__global__ __launch_bounds__(256) void k_agg1(
    const ushort* __restrict__ Xin, const int* __restrict__ cnt,
    const int* __restrict__ csr2, ushort* __restrict__ Y)
{
    int i = blockIdx.x * 4 + (threadIdx.x >> 6);
    if (i >= N_NODES) return;
    int lane = threadIdx.x & 63;
    const uint* xin = (const uint*)Xin;        // 2 bf16 per uint, 64 uints per row
    const int* row = csr2 + ((size_t)i << SLOT_SHIFT);
    int deg = cnt[i];
    float dv = deg_inv(deg);
    uint xi = xin[(size_t)i * 64 + lane];
    float a0 = dv * bflo(xi), a1 = dv * bfhi(xi);
    int e = 0;
    for (; e + 4 <= deg; e += 4) {
        int sa = row[e], sb = row[e + 1], sc = row[e + 2], sd = row[e + 3];
        float da = deg_inv(cnt[sa]), db = deg_inv(cnt[sb]);
        float dc = deg_inv(cnt[sc]), dd = deg_inv(cnt[sd]);
        uint wa = xin[(size_t)sa * 64 + lane];
        uint wb = xin[(size_t)sb * 64 + lane];
        uint wc = xin[(size_t)sc * 64 + lane];
        uint wd = xin[(size_t)sd * 64 + lane];
        a0 = fmaf(da, bflo(wa), a0); a1 = fmaf(da, bfhi(wa), a1);
        a0 = fmaf(db, bflo(wb), a0); a1 = fmaf(db, bfhi(wb), a1);
        a0 = fmaf(dc, bflo(wc), a0); a1 = fmaf(dc, bfhi(wc), a1);
        a0 = fmaf(dd, bflo(wd), a0); a1 = fmaf(dd, bfhi(wd), a1);
    }
    for (; e < deg; ++e) {
        int sa = row[e];
        float da = deg_inv(cnt[sa]);
        uint wa = xin[(size_t)sa * 64 + lane];
        a0 = fmaf(da, bflo(wa), a0); a1 = fmaf(da, bfhi(wa), a1);
    }
    uint o = (uint)f2bf(dv * a0) | ((uint)f2bf(dv * a1) << 16);
    ((uint*)Y)[(size_t)i * 64 + lane] = o;
}

// ---------------- 512-dim aggregation: X[i] = relu(dinv[i]*(sum_e g[src_e] + g[i]) + b) ----------------
// 4 nodes per block (wave per node), 8-edge unroll, uint4 full-row gathers; bucket adjacency

__global__ __launch_bounds__(256) void k_agg(
    const ushort* __restrict__ G, const int* __restrict__ cnt,
    const int* __restrict__ csr2, const float* __restrict__ bias,
    ushort* __restrict__ X)
{
    int i = blockIdx.x * 4 + (threadIdx.x >> 6);
    if (i >= N_NODES) return;
    int lane = threadIdx.x & 63;
    const uint4* g4 = (const uint4*)G;         // 8 bf16 per uint4, 64 per row
    const int* rowp = csr2 + ((size_t)i << SLOT_SHIFT);

    uint4 a = g4[(size_t)i * 64 + lane];
    float acc[8] = { bflo(a.x), bfhi(a.x), bflo(a.y), bfhi(a.y),
                     bflo(a.z), bfhi(a.z), bflo(a.w), bfhi(a.w) };

    int deg = cnt[i];
    int e = 0;
    for (; e + 8 <= deg; e += 8) {
        int s0 = rowp[e],     s1i = rowp[e + 1], s2 = rowp[e + 2], s3 = rowp[e + 3];
        int s4 = rowp[e + 4], s5 = rowp[e + 5],  s6 = rowp[e + 6], s7 = rowp[e + 7];
        uint4 w0 = g4[(size_t)s0 * 64 + lane];
        uint4 w1 = g4[(size_t)s1i * 64 + lane];
        uint4 w2 = g4[(size_t)s2 * 64 + lane];
        uint4 w3 = g4[(size_t)s3 * 64 + lane];
        uint4 w4 = g4[(size_t)s4 * 64 + lane];
        uint4 w5 = g4[(size_t)s5 * 64 + lane];
        uint4 w6 = g4[(size_t)s6 * 64 + lane];
        uint4 w7 = g4[(size_t)s7 * 64 + lane];
        add8(acc, w0); add8(acc, w1); add8(acc, w2); add8(acc, w3);
        add8(acc, w4); add8(acc, w5); add8(acc, w6); add8(acc, w7);
    }
    for (; e + 4 <= deg; e += 4) {
        int s0 = rowp[e], s1i = rowp[e + 1], s2 = rowp[e + 2], s3 = rowp[e + 3];
        uint4 w0 = g4[(size_t)s0 * 64 + lane];
        uint4 w1 = g4[(size_t)s1i * 64 + lane];
        uint4 w2 = g4[(size_t)s2 * 64 + lane];
        uint4 w3 = g4[(size_t)s3 * 64 + lane];
        add8(acc, w0); add8(acc, w1); add8(acc, w2); add8(acc, w3);
    }
    for (; e < deg; ++e) {
        int s0 = rowp[e];
        uint4 w0 = g4[(size_t)s0 * 64 + lane];
        add8(acc, w0);
    }

    float dv = deg_inv(deg);
    float4 b0 = *(const float4*)(bias + lane * 8);
    float4 b1 = *(const float4*)(bias + lane * 8 + 4);
    float bb[8] = { b0.x, b0.y, b0.z, b0.w, b1.x, b1.y, b1.z, b1.w };

    uint4 o;
    uint p[8];
    for (int j = 0; j < 8; ++j)
        p[j] = f2bf(fmaxf(fmaf(dv, acc[j], bb[j]), 0.0f));
    o.x = p[0] | (p[1] << 16);
    o.y = p[2] | (p[3] << 16);
    o.z = p[4] | (p[5] << 16);
    o.w = p[6] | (p[7] << 16);
    *(uint4*)(X + (size_t)i * HID + lane * 8) = o;
}

// ---------------- pooling: grid (N_GRAPHS, 8), 256 threads; 8 half-waves stride nodes ----------------
// X is post-relu (>=0), so 0-init max is exact.

__global__ __launch_bounds__(256) void k_pool(
    const ushort* __restrict__ X, const int* __restrict__ gstart, float* __restrict__ P)
{
    __shared__ float red[8][64];
    int g = blockIdx.x;
    int cg = blockIdx.y;           // 64-channel group
    int t = threadIdx.x;
    int hw = t >> 5;               // half-wave 0..7
    int cl = t & 31;               // uint lane: covers 2 channels
    const uint* xu = (const uint*)X;            // 256 uints per row
    size_t colbase = (size_t)cg * 32 + cl;
    int i0 = gstart[g], i1 = gstart[g + 1];
    float m0 = 0.0f, m1 = 0.0f;
    for (int i = i0 + hw; i < i1; i += 8) {
        uint v = xu[(size_t)i * 256 + colbase];
        m0 = fmaxf(m0, bflo(v));
        m1 = fmaxf(m1, bfhi(v));
    }
    red[hw][cl * 2] = m0;
    red[hw][cl * 2 + 1] = m1;
    __syncthreads();
    if (hw == 0) {
        float a = red[0][cl * 2], b = red[0][cl * 2 + 1];
        for (int q = 1; q < 8; ++q) {
            a = fmaxf(a, red[q][cl * 2]);
            b = fmaxf(b, red[q][cl * 2 + 1]);
        }
        P[(size_t)g * HID + cg * 64 + cl * 2] = a;
        P[(size_t)g * HID + cg * 64 + cl * 2 + 1] = b;
    }
}

// ---------------- FC layers: grid (graph, out-chunk of 64), 4 waves split K ----------------

__global__ __launch_bounds__(256) void k_fc(
    const float* __restrict__ in, const float* __restrict__ W,
    const float* __restrict__ b, float* __restrict__ out,
    int K, int NO, int relu)
{
    __shared__ float xs[HID];
    __shared__ float part[4][64];
    int g = blockIdx.x;
    int j0 = blockIdx.y * 64;
    int tid = threadIdx.x;
    int wave = tid >> 6, lane = tid & 63;

    for (int k = tid; k < K; k += 256) xs[k] = in[(size_t)g * K + k];
    __syncthreads();

    int j = j0 + lane;
    bool active = (j < NO);
    int kpw = K >> 2;          // K per wave (K=512 -> 128)
    int k0 = wave * kpw;
    float acc = 0.0f;
    if (active) {
        const float* wp = W + (size_t)k0 * NO + j;
        int k = 0;
        for (; k + 4 <= kpw; k += 4) {
            float w0 = wp[(size_t)(k + 0) * NO];
            float w1 = wp[(size_t)(k + 1) * NO];
            float w2 = wp[(size_t)(k + 2) * NO];
            float w3 = wp[(size_t)(k + 3) * NO];
            acc = fmaf(xs[k0 + k + 0], w0, acc);
            acc = fmaf(xs[k0 + k + 1], w1, acc);
            acc = fmaf(xs[k0 + k + 2], w2, acc);
            acc = fmaf(xs[k0 + k + 3], w3, acc);
        }
        for (; k < kpw; ++k)
            acc = fmaf(xs[k0 + k], wp[(size_t)k * NO], acc);
    }
    part[wave][lane] = acc;
    __syncthreads();
    if (wave == 0 && active) {
        float a = part[0][lane] + part[1][lane] + part[2][lane] + part[3][lane] + b[j];
        if (relu) a = fmaxf(a, 0.0f);
        out[(size_t)g * NO + j] = a;
    }
}

// ---------------- launch ----------------

extern "C" void kernel_launch(void* const* d_in, const int* in_sizes, int n_in,
                              void* d_out, int out_size, void* d_ws, size_t ws_size,
                              hipStream_t stream) {
    const float* tree_x = (const float*)d_in[0];
    const int*   ei     = (const int*)d_in[1];
    const int*   batch  = (const int*)d_in[2];
    const float* W1  = (const float*)d_in[3];  const float* b1  = (const float*)d_in[4];
    const float* W2  = (const float*)d_in[5];  const float* b2  = (const float*)d_in[6];
    const float* W3  = (const float*)d_in[7];  const float* b3  = (const float*)d_in[8];
    const float* Wf1 = (const float*)d_in[9];  const float* bf1 = (const float*)d_in[10];
    const float* Wf2 = (const float*)d_in[11]; const float* bf2 = (const float*)d_in[12];
    const float* Wf3 = (const float*)d_in[13]; const float* bf3 = (const float*)d_in[14];
    const float* Wo  = (const float*)d_in[15]; const float* bo  = (const float*)d_in[16];

    char* w = (char*)d_ws;
    size_t off = 0;
    auto alloc = [&](size_t bytes) -> void* {
        void* p = w + off;
        off += (bytes + 255) & ~(size_t)255;
        return p;
    };
    int*    cnt      = (int*)alloc((size_t)N_NODES * 4);
    int*    csr2     = (int*)alloc((size_t)N_NODES * SLOTS * 4);
    int*    gstart   = (int*)alloc((size_t)(N_GRAPHS + 1) * 4);
    ushort* xbf      = (ushort*)alloc((size_t)N_NODES * IN_DIM * 2);
    ushort* ybuf     = (ushort*)alloc((size_t)N_NODES * IN_DIM * 2);
    ushort* w1t      = (ushort*)alloc((size_t)HID * IN_DIM * 2);
    ushort* w2t      = (ushort*)alloc((size_t)HID * HID * 2);
    ushort* w3t      = (ushort*)alloc((size_t)HID * HID * 2);
    ushort* gbuf     = (ushort*)alloc((size_t)N_NODES * HID * 2);
    ushort* xbuf     = (ushort*)alloc((size_t)N_NODES * HID * 2);
    float*  P0       = (float*)alloc((size_t)N_GRAPHS * HID * 4);
    float*  P1       = (float*)alloc((size_t)N_GRAPHS * HID * 4);

    const int* esrc = ei;
    const int* edst = ei + N_EDGES;

    hipMemsetAsync(cnt, 0, (size_t)N_NODES * 4, stream);
    k_prep<<<PB_BOUNDS, 256, 0, stream>>>(esrc, edst, cnt, csr2, tree_x, xbf,
                                          W1, w1t, W2, w2t, W3, w3t, batch, gstart);

    dim3 gemm_grid((N_NODES + 127) / 128, HID / 128);

    // layer 1: agg-first (128-dim gather), then GEMM with fused bias+relu
    k_agg1<<<N_NODES / 4, 256, 0, stream>>>(xbf, cnt, csr2, ybuf);
    k_gemm<<<gemm_grid, 256, 0, stream>>>(ybuf, w1t, cnt, b1, xbuf, N_NODES, IN_DIM, 1);
    // layer 2
    k_gemm<<<gemm_grid, 256, 0, stream>>>(xbuf, w2t, cnt, b2, gbuf, N_NODES, HID, 0);
    k_agg<<<N_NODES / 4, 256, 0, stream>>>(gbuf, cnt, csr2, b2, xbuf);
    // layer 3
    k_gemm<<<gemm_grid, 256, 0, stream>>>(xbuf, w3t, cnt, b3, gbuf, N_NODES, HID, 0);
    k_agg<<<N_NODES / 4, 256, 0, stream>>>(gbuf, cnt, csr2, b3, xbuf);

    // pool
    k_pool<<<dim3(N_GRAPHS, 8), 256, 0, stream>>>(xbuf, gstart, P0);

    // FC head
    k_fc<<<dim3(N_GRAPHS, HID / 64), 256, 0, stream>>>(P0, Wf1, bf1, P1, HID, HID, 1);
    k_fc<<<dim3(N_GRAPHS, HID / 64), 256, 0, stream>>>(P1, Wf2, bf2, P0, HID, HID, 1);
    k_fc<<<dim3(N_GRAPHS, HID / 64), 256, 0, stream>>>(P0, Wf3, bf3, P1, HID, HID, 1);
    k_fc<<<dim3(N_GRAPHS, 1), 256, 0, stream>>>(P1, Wo, bo, (float*)d_out, HID, N_ACT, 0);
}